// Round 4
// baseline (315.039 us; speedup 1.0000x reference)
//
#include <hip/hip_runtime.h>

#define HEAD_NUM 32
#define D_K 128
#define HIDDEN 4096
#define MAX_BS 16
#define MAX_SEQ 2048
#define NCHUNK 8        // seq chunks for flash-decoding split
#define CHUNK 256       // MAX_SEQ / NCHUNK
#define NATTN (HEAD_NUM * MAX_BS * NCHUNK)   // 4096 attention blocks
#define NKV   (16 * 32 * 2)                  // 1024 k/v-projection blocks

// ---------------------------------------------------------------------------
// Kernel 1: q = x @ w_q only (gates attention). k-split x64 -> 1024 blocks.
// ---------------------------------------------------------------------------
__global__ __launch_bounds__(256) void qproj_kernel(
    const float* __restrict__ x,
    const float* __restrict__ w_q,
    float* __restrict__ qbuf)     // [MAX_BS][HIDDEN], pre-zeroed
{
    __shared__ float xs[MAX_BS][64];
    const int colTile = blockIdx.x;   // 0..15
    const int kChunk  = blockIdx.y;   // 0..63 (chunks of 64)
    const int tid     = threadIdx.x;

    {   // stage x chunk: 16 rows x 64 = 256 float4 -> one per thread
        int b = tid >> 4;
        int f = tid & 15;
        *reinterpret_cast<float4*>(&xs[b][f * 4]) =
            *reinterpret_cast<const float4*>(&x[b * HIDDEN + kChunk * 64 + f * 4]);
    }
    __syncthreads();

    const int col = colTile * 256 + tid;
    float acc[MAX_BS];
    #pragma unroll
    for (int b = 0; b < MAX_BS; ++b) acc[b] = 0.f;

    const float* wcol = w_q + (size_t)(kChunk * 64) * HIDDEN + col;
    #pragma unroll 4
    for (int ii = 0; ii < 64; ++ii) {
        float w = wcol[(size_t)ii * HIDDEN];   // coalesced across lanes
        #pragma unroll
        for (int b = 0; b < MAX_BS; ++b)
            acc[b] = fmaf(xs[b][ii], w, acc[b]);
    }

    #pragma unroll
    for (int b = 0; b < MAX_BS; ++b)
        atomicAdd(&qbuf[b * HIDDEN + col], acc[b]);
}

// ---------------------------------------------------------------------------
// Kernel 2 (fused): attention-over-cache partials  +  k/v projections.
// Blocks [0, NATTN): one (h,b,chunk) each, cache positions s < start_pos only.
// Blocks [NATTN, NATTN+NKV): k-split tiles of x@{w_k,w_v} -> qkv sections 1,2.
// The two roles are data-independent, so the 128 MB of w_k/w_v traffic
// overlaps the 1.07 GB cache stream instead of serializing in front of it.
// ---------------------------------------------------------------------------
__global__ __launch_bounds__(256) void fused_attn_kv_kernel(
    const float* __restrict__ x,
    const float* __restrict__ w_k,
    const float* __restrict__ w_v,
    const float* __restrict__ cache_k,
    const float* __restrict__ cache_v,
    float* __restrict__ qkv,        // [3][MAX_BS][HIDDEN]; [0]=q ready, [1],[2] pre-zeroed
    const int*   __restrict__ start_pos_p,
    float* __restrict__ part_o,     // [B][H][NCHUNK][D_K]
    float* __restrict__ part_ml)    // [B][H][NCHUNK][2]
{
    __shared__ float smem[MAX_BS * 128];   // 8 KB, aliased by both roles
    const int bid = blockIdx.x;
    const int tid = threadIdx.x;

    if (bid < NATTN) {
        // ---------------- attention-over-cache role -----------------------
        float* sc  = smem;                                              // [256]
        float* red = smem + 256;                                        // [8]
        float (*partial)[D_K] = reinterpret_cast<float(*)[D_K]>(smem + 264); // [8][128], 16B-aligned

        const int c = bid & 7;
        const int b = (bid >> 3) & 15;
        const int h = bid >> 7;
        const int start_pos = *start_pos_p;
        const int s0 = c * CHUNK;

        const float* q = qkv + b * HIDDEN + h * D_K;
        const int lane32 = tid & 31;
        const int grp    = tid >> 5;         // 0..7
        const int wid    = tid >> 6;         // 0..3

        const float4 qf = *reinterpret_cast<const float4*>(&q[lane32 * 4]);
        const float scale = 0.08838834764831845f;   // 1/sqrt(128)

        sc[tid] = -INFINITY;
        __syncthreads();

        // scores (cache rows only: s < start_pos)
        for (int r = grp; r < CHUNK; r += 8) {
            const int s = s0 + r;
            if (s >= start_pos) break;
            const float* krow = cache_k + (((size_t)b * MAX_SEQ + s) * HEAD_NUM + h) * D_K;
            const float4 kf = *reinterpret_cast<const float4*>(&krow[lane32 * 4]);
            float p = qf.x * kf.x + qf.y * kf.y + qf.z * kf.z + qf.w * kf.w;
            p += __shfl_xor(p, 16);
            p += __shfl_xor(p, 8);
            p += __shfl_xor(p, 4);
            p += __shfl_xor(p, 2);
            p += __shfl_xor(p, 1);
            if (lane32 == 0) sc[r] = p * scale;
        }
        __syncthreads();

        // local softmax stats
        float m = sc[tid];
        #pragma unroll
        for (int off = 32; off; off >>= 1) m = fmaxf(m, __shfl_xor(m, off));
        if ((tid & 63) == 0) red[wid] = m;
        __syncthreads();
        m = fmaxf(fmaxf(red[0], red[1]), fmaxf(red[2], red[3]));

        const float raw = sc[tid];
        const float e = (raw == -INFINITY) ? 0.f : __expf(raw - m);
        __syncthreads();           // everyone done reading sc before overwrite
        sc[tid] = e;
        float sum = e;
        #pragma unroll
        for (int off = 32; off; off >>= 1) sum += __shfl_xor(sum, off);
        if ((tid & 63) == 0) red[4 + wid] = sum;
        __syncthreads();
        sum = red[4] + red[5] + red[6] + red[7];

        // unnormalized PV
        float4 accv = {0.f, 0.f, 0.f, 0.f};
        for (int r = grp; r < CHUNK; r += 8) {
            const int s = s0 + r;
            if (s >= start_pos) break;
            const float* vrow = cache_v + (((size_t)b * MAX_SEQ + s) * HEAD_NUM + h) * D_K;
            const float4 vf = *reinterpret_cast<const float4*>(&vrow[lane32 * 4]);
            const float p = sc[r];
            accv.x = fmaf(p, vf.x, accv.x);
            accv.y = fmaf(p, vf.y, accv.y);
            accv.z = fmaf(p, vf.z, accv.z);
            accv.w = fmaf(p, vf.w, accv.w);
        }
        *reinterpret_cast<float4*>(&partial[grp][lane32 * 4]) = accv;
        __syncthreads();

        const size_t base = (size_t)(b * HEAD_NUM + h) * NCHUNK + c;
        if (tid < D_K) {
            float r = 0.f;
            #pragma unroll
            for (int g = 0; g < 8; ++g) r += partial[g][tid];
            part_o[base * D_K + tid] = r;
        }
        if (tid == 0) {
            part_ml[base * 2 + 0] = m;
            part_ml[base * 2 + 1] = sum;
        }
    } else {
        // ---------------- k/v projection role -----------------------------
        float (*xs)[128] = reinterpret_cast<float(*)[128]>(smem);
        const int t       = bid - NATTN;
        const int colTile = t & 15;          // 0..15
        const int kChunk  = (t >> 4) & 31;   // 0..31 (chunks of 128)
        const int mat     = 1 + (t >> 9);    // 1 (k) or 2 (v)

        const float* W = (mat == 1) ? w_k : w_v;
        float* outp = qkv + (size_t)mat * (MAX_BS * HIDDEN);

        for (int idx = tid; idx < MAX_BS * 128 / 4; idx += 256) {
            int b = idx >> 5;
            int f = idx & 31;
            *reinterpret_cast<float4*>(&xs[b][f * 4]) =
                *reinterpret_cast<const float4*>(&x[b * HIDDEN + kChunk * 128 + f * 4]);
        }
        __syncthreads();

        const int col = colTile * 256 + tid;
        float acc[MAX_BS];
        #pragma unroll
        for (int b = 0; b < MAX_BS; ++b) acc[b] = 0.f;

        const float* wcol = W + (size_t)(kChunk * 128) * HIDDEN + col;
        #pragma unroll 4
        for (int ii = 0; ii < 128; ++ii) {
            float w = wcol[(size_t)ii * HIDDEN];
            #pragma unroll
            for (int b = 0; b < MAX_BS; ++b)
                acc[b] = fmaf(xs[b][ii], w, acc[b]);
        }

        #pragma unroll
        for (int b = 0; b < MAX_BS; ++b)
            atomicAdd(&outp[b * HIDDEN + col], acc[b]);
    }
}

// ---------------------------------------------------------------------------
// Kernel 3: combine chunk partials + the new-token (s = start_pos) term.
// score = scale * dot(q, k_new) computed here; merged as an extra partial.
// ---------------------------------------------------------------------------
__global__ __launch_bounds__(128) void combine_kernel(
    const float* __restrict__ qkv,
    const float* __restrict__ part_o,
    const float* __restrict__ part_ml,
    float* __restrict__ attn_out)
{
    const int h   = blockIdx.x;
    const int b   = blockIdx.y;
    const int tid = threadIdx.x;     // 0..127
    __shared__ float redS[2];

    const float* q    = qkv + b * HIDDEN + h * D_K;
    const float* knew = qkv + 1 * (MAX_BS * HIDDEN) + b * HIDDEN + h * D_K;
    const float* vnew = qkv + 2 * (MAX_BS * HIDDEN) + b * HIDDEN + h * D_K;

    float pp = q[tid] * knew[tid];
    #pragma unroll
    for (int off = 32; off; off >>= 1) pp += __shfl_xor(pp, off);
    if ((tid & 63) == 0) redS[tid >> 6] = pp;
    __syncthreads();
    const float score = (redS[0] + redS[1]) * 0.08838834764831845f;

    const size_t base = (size_t)(b * HEAD_NUM + h) * NCHUNK;
    float mv[NCHUNK];
    float M = score;
    #pragma unroll
    for (int c = 0; c < NCHUNK; ++c) {
        mv[c] = part_ml[(base + c) * 2];
        M = fmaxf(M, mv[c]);
    }
    float acc = 0.f, l = 0.f;
    #pragma unroll
    for (int c = 0; c < NCHUNK; ++c) {
        const float w = __expf(mv[c] - M);
        acc += w * part_o[(base + c) * D_K + tid];
        l   += w * part_ml[(base + c) * 2 + 1];
    }
    const float wn = __expf(score - M);
    acc += wn * vnew[tid];
    l   += wn;

    attn_out[b * HIDDEN + h * D_K + tid] = acc / l;
}

// ---------------------------------------------------------------------------
// Kernel 4: out = attn_out @ w_o. k-split x32 (512 blocks).
// ---------------------------------------------------------------------------
__global__ __launch_bounds__(256) void oproj_kernel(
    const float* __restrict__ attn_out,
    const float* __restrict__ w_o,
    float* __restrict__ out)
{
    __shared__ float xs[MAX_BS][128];
    const int colTile = blockIdx.x;   // 0..15
    const int kChunk  = blockIdx.y;   // 0..31 (chunks of 128)
    const int tid     = threadIdx.x;

    for (int idx = tid; idx < MAX_BS * 128 / 4; idx += 256) {
        int b = idx >> 5;
        int f = idx & 31;
        *reinterpret_cast<float4*>(&xs[b][f * 4]) =
            *reinterpret_cast<const float4*>(&attn_out[b * HIDDEN + kChunk * 128 + f * 4]);
    }
    __syncthreads();

    const int col = colTile * 256 + tid;
    float acc[MAX_BS];
    #pragma unroll
    for (int b = 0; b < MAX_BS; ++b) acc[b] = 0.f;

    const float* wcol = w_o + (size_t)(kChunk * 128) * HIDDEN + col;
    #pragma unroll 4
    for (int ii = 0; ii < 128; ++ii) {
        float w = wcol[(size_t)ii * HIDDEN];
        #pragma unroll
        for (int b = 0; b < MAX_BS; ++b)
            acc[b] = fmaf(xs[b][ii], w, acc[b]);
    }

    #pragma unroll
    for (int b = 0; b < MAX_BS; ++b)
        atomicAdd(&out[b * HIDDEN + col], acc[b]);
}

extern "C" void kernel_launch(void* const* d_in, const int* in_sizes, int n_in,
                              void* d_out, int out_size, void* d_ws, size_t ws_size,
                              hipStream_t stream) {
    const float* x       = (const float*)d_in[0];
    const float* cache_k = (const float*)d_in[1];
    const float* cache_v = (const float*)d_in[2];
    const float* w_q     = (const float*)d_in[3];
    const float* w_k     = (const float*)d_in[4];
    const float* w_v     = (const float*)d_in[5];
    const float* w_o     = (const float*)d_in[6];
    const int*   start_pos = (const int*)d_in[7];

    float* out      = (float*)d_out;
    float* qkv      = (float*)d_ws;                         // [3][16][4096]
    float* attn_out = qkv + 3 * MAX_BS * HIDDEN;            // [16][4096]
    float* part_o   = attn_out + MAX_BS * HIDDEN;           // [16][32][8][128]
    float* part_ml  = part_o + (size_t)MAX_BS * HEAD_NUM * NCHUNK * D_K; // [16][32][8][2]

    hipMemsetAsync(qkv, 0, (size_t)3 * MAX_BS * HIDDEN * sizeof(float), stream);
    hipMemsetAsync(d_out, 0, (size_t)out_size * sizeof(float), stream);

    qproj_kernel<<<dim3(16, 64), 256, 0, stream>>>(x, w_q, qkv);
    fused_attn_kv_kernel<<<dim3(NATTN + NKV), 256, 0, stream>>>(
        x, w_k, w_v, cache_k, cache_v, qkv, start_pos, part_o, part_ml);
    combine_kernel<<<dim3(HEAD_NUM, MAX_BS), 128, 0, stream>>>(
        qkv, part_o, part_ml, attn_out);
    oproj_kernel<<<dim3(16, 32), 256, 0, stream>>>(attn_out, w_o, out);
}

// Round 5
// 285.239 us; speedup vs baseline: 1.1045x; 1.1045x over previous
//
#include <hip/hip_runtime.h>

#define HEAD_NUM 32
#define D_K 128
#define HIDDEN 4096
#define MAX_BS 16
#define MAX_SEQ 2048
#define NCHUNK 8        // seq chunks for flash-decoding split
#define CHUNK 256       // MAX_SEQ / NCHUNK
#define NSPLIT 32       // k-split for GEMVs (chunks of 128 along reduction)

// ---------------------------------------------------------------------------
// Kernel 1: k-split GEMV for q,k,v. Writes per-chunk partials (no atomics,
// no memset needed). partials layout: [mat][kChunk][b][col].
// ---------------------------------------------------------------------------
__global__ __launch_bounds__(256) void qkv_gemv_kernel(
    const float* __restrict__ x,
    const float* __restrict__ w_q,
    const float* __restrict__ w_k,
    const float* __restrict__ w_v,
    float* __restrict__ partials)   // [3][NSPLIT][MAX_BS][HIDDEN]
{
    __shared__ float xs[MAX_BS][128];
    const int colTile = blockIdx.x;   // 0..15
    const int kChunk  = blockIdx.y;   // 0..31
    const int mat     = blockIdx.z;   // 0..2
    const int tid     = threadIdx.x;

    const float* W = (mat == 0) ? w_q : (mat == 1) ? w_k : w_v;

    for (int idx = tid; idx < MAX_BS * 128 / 4; idx += 256) {
        int b = idx >> 5;
        int f = idx & 31;
        *reinterpret_cast<float4*>(&xs[b][f * 4]) =
            *reinterpret_cast<const float4*>(&x[b * HIDDEN + kChunk * 128 + f * 4]);
    }
    __syncthreads();

    const int col = colTile * 256 + tid;
    float acc[MAX_BS];
    #pragma unroll
    for (int b = 0; b < MAX_BS; ++b) acc[b] = 0.f;

    const float* wcol = W + (size_t)(kChunk * 128) * HIDDEN + col;
    #pragma unroll 4
    for (int ii = 0; ii < 128; ++ii) {
        float w = wcol[(size_t)ii * HIDDEN];   // coalesced across lanes
        #pragma unroll
        for (int b = 0; b < MAX_BS; ++b)
            acc[b] = fmaf(xs[b][ii], w, acc[b]);
    }

    float* outp = partials + ((size_t)(mat * NSPLIT + kChunk) * MAX_BS) * HIDDEN + col;
    #pragma unroll
    for (int b = 0; b < MAX_BS; ++b)
        outp[(size_t)b * HIDDEN] = acc[b];
}

// ---------------------------------------------------------------------------
// Kernel 2: reduce qkv partials -> qkv[3][MAX_BS][HIDDEN].
// ---------------------------------------------------------------------------
__global__ __launch_bounds__(256) void qkv_reduce_kernel(
    const float* __restrict__ partials,
    float* __restrict__ qkv)
{
    const int idx = blockIdx.x * 256 + threadIdx.x;   // 0 .. 3*16*4096-1
    const int mat = idx / (MAX_BS * HIDDEN);
    const int rem = idx - mat * (MAX_BS * HIDDEN);
    const float* p = partials + (size_t)mat * NSPLIT * MAX_BS * HIDDEN + rem;
    float s = 0.f;
    #pragma unroll
    for (int c = 0; c < NSPLIT; ++c)
        s += p[(size_t)c * MAX_BS * HIDDEN];
    qkv[idx] = s;
}

// ---------------------------------------------------------------------------
// Kernel 3: flash-decoding partials over cache rows (s < start_pos).
// Trip count precomputed (no break) so loops can unroll/pipeline.
// ---------------------------------------------------------------------------
__global__ __launch_bounds__(256) void attn_partial_kernel(
    const float* __restrict__ cache_k,
    const float* __restrict__ cache_v,
    const float* __restrict__ qkv,
    const int*   __restrict__ start_pos_p,
    float* __restrict__ part_o,    // [B][H][NCHUNK][D_K]
    float* __restrict__ part_ml)   // [B][H][NCHUNK][2]
{
    const int h   = blockIdx.x;
    const int b   = blockIdx.y;
    const int c   = blockIdx.z;
    const int tid = threadIdx.x;
    const int start_pos = *start_pos_p;
    const int s0        = c * CHUNK;
    int nrows = start_pos - s0;                 // cache rows only
    nrows = (nrows < 0) ? 0 : (nrows > CHUNK ? CHUNK : nrows);

    __shared__ float sc[CHUNK];
    __shared__ float red[8];
    __shared__ float partial[8][D_K];

    const float* q = qkv + b * HIDDEN + h * D_K;
    const int lane32 = tid & 31;
    const int grp    = tid >> 5;         // 0..7
    const int wid    = tid >> 6;         // 0..3

    const float4 qf = *reinterpret_cast<const float4*>(&q[lane32 * 4]);
    const float scale = 0.08838834764831845f;   // 1/sqrt(128)

    sc[tid] = -INFINITY;
    __syncthreads();

    // ---- scores ----------------------------------------------------------
    const float* kbase = cache_k + (((size_t)b * MAX_SEQ + s0) * HEAD_NUM + h) * D_K;
    #pragma unroll 4
    for (int r = grp; r < nrows; r += 8) {
        const float4 kf = *reinterpret_cast<const float4*>(
            &kbase[(size_t)r * (HEAD_NUM * D_K) + lane32 * 4]);
        float p = qf.x * kf.x + qf.y * kf.y + qf.z * kf.z + qf.w * kf.w;
        p += __shfl_xor(p, 16);
        p += __shfl_xor(p, 8);
        p += __shfl_xor(p, 4);
        p += __shfl_xor(p, 2);
        p += __shfl_xor(p, 1);
        if (lane32 == 0) sc[r] = p * scale;
    }
    __syncthreads();

    // ---- local softmax stats --------------------------------------------
    float m = sc[tid];
    #pragma unroll
    for (int off = 32; off; off >>= 1) m = fmaxf(m, __shfl_xor(m, off));
    if ((tid & 63) == 0) red[wid] = m;
    __syncthreads();
    m = fmaxf(fmaxf(red[0], red[1]), fmaxf(red[2], red[3]));

    const float raw = sc[tid];
    const float e = (raw == -INFINITY) ? 0.f : __expf(raw - m);
    __syncthreads();
    sc[tid] = e;
    float sum = e;
    #pragma unroll
    for (int off = 32; off; off >>= 1) sum += __shfl_xor(sum, off);
    if ((tid & 63) == 0) red[4 + wid] = sum;
    __syncthreads();
    sum = red[4] + red[5] + red[6] + red[7];

    // ---- unnormalized PV -------------------------------------------------
    float4 accv = {0.f, 0.f, 0.f, 0.f};
    const float* vbase = cache_v + (((size_t)b * MAX_SEQ + s0) * HEAD_NUM + h) * D_K;
    #pragma unroll 4
    for (int r = grp; r < nrows; r += 8) {
        const float4 vf = *reinterpret_cast<const float4*>(
            &vbase[(size_t)r * (HEAD_NUM * D_K) + lane32 * 4]);
        const float p = sc[r];
        accv.x = fmaf(p, vf.x, accv.x);
        accv.y = fmaf(p, vf.y, accv.y);
        accv.z = fmaf(p, vf.z, accv.z);
        accv.w = fmaf(p, vf.w, accv.w);
    }
    *reinterpret_cast<float4*>(&partial[grp][lane32 * 4]) = accv;
    __syncthreads();

    const size_t base = (size_t)(b * HEAD_NUM + h) * NCHUNK + c;
    if (tid < D_K) {
        float r = 0.f;
        #pragma unroll
        for (int g = 0; g < 8; ++g) r += partial[g][tid];
        part_o[base * D_K + tid] = r;
    }
    if (tid == 0) {
        part_ml[base * 2 + 0] = m;
        part_ml[base * 2 + 1] = sum;
    }
}

// ---------------------------------------------------------------------------
// Kernel 4: combine chunk partials + new-token (s = start_pos) term.
// ---------------------------------------------------------------------------
__global__ __launch_bounds__(128) void combine_kernel(
    const float* __restrict__ qkv,
    const float* __restrict__ part_o,
    const float* __restrict__ part_ml,
    float* __restrict__ attn_out)
{
    const int h   = blockIdx.x;
    const int b   = blockIdx.y;
    const int tid = threadIdx.x;     // 0..127
    __shared__ float redS[2];

    const float* q    = qkv + b * HIDDEN + h * D_K;
    const float* knew = qkv + 1 * (MAX_BS * HIDDEN) + b * HIDDEN + h * D_K;
    const float* vnew = qkv + 2 * (MAX_BS * HIDDEN) + b * HIDDEN + h * D_K;

    float pp = q[tid] * knew[tid];
    #pragma unroll
    for (int off = 32; off; off >>= 1) pp += __shfl_xor(pp, off);
    if ((tid & 63) == 0) redS[tid >> 6] = pp;
    __syncthreads();
    const float score = (redS[0] + redS[1]) * 0.08838834764831845f;

    const size_t base = (size_t)(b * HEAD_NUM + h) * NCHUNK;
    float mv[NCHUNK];
    float M = score;
    #pragma unroll
    for (int c = 0; c < NCHUNK; ++c) {
        mv[c] = part_ml[(base + c) * 2];
        M = fmaxf(M, mv[c]);
    }
    float acc = 0.f, l = 0.f;
    #pragma unroll
    for (int c = 0; c < NCHUNK; ++c) {
        const float w = __expf(mv[c] - M);
        acc += w * part_o[(base + c) * D_K + tid];
        l   += w * part_ml[(base + c) * 2 + 1];
    }
    const float wn = __expf(score - M);
    acc += wn * vnew[tid];
    l   += wn;

    attn_out[b * HIDDEN + h * D_K + tid] = acc / l;
}

// ---------------------------------------------------------------------------
// Kernel 5: oproj GEMV partials (no atomics).
// partials layout: [kChunk][b][col].
// ---------------------------------------------------------------------------
__global__ __launch_bounds__(256) void oproj_gemv_kernel(
    const float* __restrict__ attn_out,
    const float* __restrict__ w_o,
    float* __restrict__ partials)   // [NSPLIT][MAX_BS][HIDDEN]
{
    __shared__ float xs[MAX_BS][128];
    const int colTile = blockIdx.x;   // 0..15
    const int kChunk  = blockIdx.y;   // 0..31
    const int tid     = threadIdx.x;

    for (int idx = tid; idx < MAX_BS * 128 / 4; idx += 256) {
        int b = idx >> 5;
        int f = idx & 31;
        *reinterpret_cast<float4*>(&xs[b][f * 4]) =
            *reinterpret_cast<const float4*>(&attn_out[b * HIDDEN + kChunk * 128 + f * 4]);
    }
    __syncthreads();

    const int col = colTile * 256 + tid;
    float acc[MAX_BS];
    #pragma unroll
    for (int b = 0; b < MAX_BS; ++b) acc[b] = 0.f;

    const float* wcol = w_o + (size_t)(kChunk * 128) * HIDDEN + col;
    #pragma unroll 4
    for (int ii = 0; ii < 128; ++ii) {
        float w = wcol[(size_t)ii * HIDDEN];
        #pragma unroll
        for (int b = 0; b < MAX_BS; ++b)
            acc[b] = fmaf(xs[b][ii], w, acc[b]);
    }

    float* outp = partials + (size_t)kChunk * MAX_BS * HIDDEN + col;
    #pragma unroll
    for (int b = 0; b < MAX_BS; ++b)
        outp[(size_t)b * HIDDEN] = acc[b];
}

// ---------------------------------------------------------------------------
// Kernel 6: reduce oproj partials -> d_out (fully overwrites; no memset).
// ---------------------------------------------------------------------------
__global__ __launch_bounds__(256) void oproj_reduce_kernel(
    const float* __restrict__ partials,
    float* __restrict__ out)
{
    const int idx = blockIdx.x * 256 + threadIdx.x;   // 0 .. 16*4096-1
    const float* p = partials + idx;
    float s = 0.f;
    #pragma unroll
    for (int c = 0; c < NSPLIT; ++c)
        s += p[(size_t)c * MAX_BS * HIDDEN];
    out[idx] = s;
}

extern "C" void kernel_launch(void* const* d_in, const int* in_sizes, int n_in,
                              void* d_out, int out_size, void* d_ws, size_t ws_size,
                              hipStream_t stream) {
    const float* x       = (const float*)d_in[0];
    const float* cache_k = (const float*)d_in[1];
    const float* cache_v = (const float*)d_in[2];
    const float* w_q     = (const float*)d_in[3];
    const float* w_k     = (const float*)d_in[4];
    const float* w_v     = (const float*)d_in[5];
    const float* w_o     = (const float*)d_in[6];
    const int*   start_pos = (const int*)d_in[7];

    float* out      = (float*)d_out;
    float* qkv      = (float*)d_ws;                          // [3][16][4096]
    float* attn_out = qkv + 3 * MAX_BS * HIDDEN;             // [16][4096]
    float* part_o   = attn_out + MAX_BS * HIDDEN;            // [16][32][8][128]
    float* part_ml  = part_o + (size_t)MAX_BS * HEAD_NUM * NCHUNK * D_K;  // [16][32][8][2]
    float* pq       = part_ml + (size_t)MAX_BS * HEAD_NUM * NCHUNK * 2;   // [3][32][16][4096]
    float* po       = pq + (size_t)3 * NSPLIT * MAX_BS * HIDDEN;          // [32][16][4096]

    qkv_gemv_kernel<<<dim3(16, NSPLIT, 3), 256, 0, stream>>>(x, w_q, w_k, w_v, pq);
    qkv_reduce_kernel<<<dim3(3 * MAX_BS * HIDDEN / 256), 256, 0, stream>>>(pq, qkv);
    attn_partial_kernel<<<dim3(HEAD_NUM, MAX_BS, NCHUNK), 256, 0, stream>>>(
        cache_k, cache_v, qkv, start_pos, part_o, part_ml);
    combine_kernel<<<dim3(HEAD_NUM, MAX_BS), 128, 0, stream>>>(
        qkv, part_o, part_ml, attn_out);
    oproj_gemv_kernel<<<dim3(16, NSPLIT), 256, 0, stream>>>(attn_out, w_o, po);
    oproj_reduce_kernel<<<dim3(MAX_BS * HIDDEN / 256), 256, 0, stream>>>(po, out);
}

// Round 6
// 275.040 us; speedup vs baseline: 1.1454x; 1.0371x over previous
//
#include <hip/hip_runtime.h>

#define HEAD_NUM 32
#define D_K 128
#define HIDDEN 4096
#define MAX_BS 16
#define MAX_SEQ 2048
#define NCHUNK 8        // seq chunks for flash-decoding split
#define CHUNK 256       // MAX_SEQ / NCHUNK

// ---------------------------------------------------------------------------
// Kernel 1: q/k/v = x @ {w_q,w_k,w_v}. k-split x32 (1536 blocks), atomics
// into memset-zeroed qkv. (R2-measured structure: 269us total anchor.)
// ---------------------------------------------------------------------------
__global__ __launch_bounds__(256) void qkv_kernel(
    const float* __restrict__ x,
    const float* __restrict__ w_q,
    const float* __restrict__ w_k,
    const float* __restrict__ w_v,
    float* __restrict__ qkv)     // [3][MAX_BS][HIDDEN], pre-zeroed
{
    __shared__ float xs[MAX_BS][128];
    const int colTile = blockIdx.x;   // 0..15
    const int kChunk  = blockIdx.y;   // 0..31
    const int mat     = blockIdx.z;   // 0..2
    const int tid     = threadIdx.x;

    const float* W = (mat == 0) ? w_q : (mat == 1) ? w_k : w_v;
    float* outp = qkv + (size_t)mat * (MAX_BS * HIDDEN);

    for (int idx = tid; idx < MAX_BS * 128 / 4; idx += 256) {
        int b = idx >> 5;
        int f = idx & 31;
        *reinterpret_cast<float4*>(&xs[b][f * 4]) =
            *reinterpret_cast<const float4*>(&x[b * HIDDEN + kChunk * 128 + f * 4]);
    }
    __syncthreads();

    const int col = colTile * 256 + tid;
    float acc[MAX_BS];
    #pragma unroll
    for (int b = 0; b < MAX_BS; ++b) acc[b] = 0.f;

    const float* wcol = W + (size_t)(kChunk * 128) * HIDDEN + col;
    #pragma unroll 4
    for (int ii = 0; ii < 128; ++ii) {
        float w = wcol[(size_t)ii * HIDDEN];   // coalesced across lanes
        #pragma unroll
        for (int b = 0; b < MAX_BS; ++b)
            acc[b] = fmaf(xs[b][ii], w, acc[b]);
    }

    #pragma unroll
    for (int b = 0; b < MAX_BS; ++b)
        atomicAdd(&outp[b * HIDDEN + col], acc[b]);
}

// ---------------------------------------------------------------------------
// Kernel 2: flash-decoding partials. 256 thr = 16 groups x 16 lanes.
// Each group: 16 rows, 32 B/lane (2x float4) -> 2x bytes in flight vs 32-lane
// rows, 4-deep shuffle reduce. FIXED 256-row trip count: the s==start_pos row
// (chunk 7 only) is loaded but masked to -INF at score write; V gets p=0.
// ---------------------------------------------------------------------------
__global__ __launch_bounds__(256) void attn_partial_kernel(
    const float* __restrict__ cache_k,
    const float* __restrict__ cache_v,
    const float* __restrict__ qkv,
    const int*   __restrict__ start_pos_p,
    float* __restrict__ part_o,    // [B][H][NCHUNK][D_K]
    float* __restrict__ part_ml)   // [B][H][NCHUNK][2]
{
    const int h   = blockIdx.x;
    const int b   = blockIdx.y;
    const int c   = blockIdx.z;
    const int tid = threadIdx.x;
    const int start_pos = *start_pos_p;
    const int s0        = c * CHUNK;

    __shared__ float sc[CHUNK];          // 1 KB
    __shared__ float red[8];
    __shared__ float partial[16][D_K];   // 8 KB

    const int lane16 = tid & 15;
    const int grp    = tid >> 4;         // 0..15
    const int wid    = tid >> 6;         // 0..3

    const float* q = qkv + b * HIDDEN + h * D_K;
    const float4 q0 = *reinterpret_cast<const float4*>(&q[lane16 * 8]);
    const float4 q1 = *reinterpret_cast<const float4*>(&q[lane16 * 8 + 4]);
    const float scale = 0.08838834764831845f;   // 1/sqrt(128)

    const size_t rowstride = (size_t)HEAD_NUM * D_K;   // 4096 floats
    const float* kbase = cache_k + (((size_t)b * MAX_SEQ + s0) * HEAD_NUM + h) * D_K;
    const float* vbase = cache_v + (((size_t)b * MAX_SEQ + s0) * HEAD_NUM + h) * D_K;

    // ---- phase A: scores (fixed trip, 16 rows per group) -----------------
    #pragma unroll 4
    for (int it = 0; it < 16; ++it) {
        const int r = it * 16 + grp;     // 16 consecutive rows in flight
        const float* krow = kbase + (size_t)r * rowstride + lane16 * 8;
        const float4 k0 = *reinterpret_cast<const float4*>(krow);
        const float4 k1 = *reinterpret_cast<const float4*>(krow + 4);
        float p = q0.x * k0.x + q0.y * k0.y + q0.z * k0.z + q0.w * k0.w
                + q1.x * k1.x + q1.y * k1.y + q1.z * k1.z + q1.w * k1.w;
        p += __shfl_xor(p, 8);
        p += __shfl_xor(p, 4);
        p += __shfl_xor(p, 2);
        p += __shfl_xor(p, 1);
        if (lane16 == 0)
            sc[r] = (s0 + r < start_pos) ? p * scale : -INFINITY;
    }
    __syncthreads();

    // ---- phase B: softmax stats (thread tid owns sc[tid]) ----------------
    float m = sc[tid];
    #pragma unroll
    for (int off = 32; off; off >>= 1) m = fmaxf(m, __shfl_xor(m, off));
    if ((tid & 63) == 0) red[wid] = m;
    __syncthreads();
    m = fmaxf(fmaxf(red[0], red[1]), fmaxf(red[2], red[3]));

    const float raw = sc[tid];
    const float e = (raw == -INFINITY) ? 0.f : __expf(raw - m);
    __syncthreads();
    sc[tid] = e;
    float sum = e;
    #pragma unroll
    for (int off = 32; off; off >>= 1) sum += __shfl_xor(sum, off);
    if ((tid & 63) == 0) red[4 + wid] = sum;
    __syncthreads();
    sum = red[4] + red[5] + red[6] + red[7];

    // ---- phase C: unnormalized PV (fixed trip; masked rows have p=0) -----
    float4 a0 = {0.f, 0.f, 0.f, 0.f};
    float4 a1 = {0.f, 0.f, 0.f, 0.f};
    #pragma unroll 4
    for (int it = 0; it < 16; ++it) {
        const int r = it * 16 + grp;
        const float* vrow = vbase + (size_t)r * rowstride + lane16 * 8;
        const float4 v0 = *reinterpret_cast<const float4*>(vrow);
        const float4 v1 = *reinterpret_cast<const float4*>(vrow + 4);
        const float p = sc[r];
        a0.x = fmaf(p, v0.x, a0.x);  a0.y = fmaf(p, v0.y, a0.y);
        a0.z = fmaf(p, v0.z, a0.z);  a0.w = fmaf(p, v0.w, a0.w);
        a1.x = fmaf(p, v1.x, a1.x);  a1.y = fmaf(p, v1.y, a1.y);
        a1.z = fmaf(p, v1.z, a1.z);  a1.w = fmaf(p, v1.w, a1.w);
    }
    *reinterpret_cast<float4*>(&partial[grp][lane16 * 8])     = a0;
    *reinterpret_cast<float4*>(&partial[grp][lane16 * 8 + 4]) = a1;
    __syncthreads();

    const size_t base = (size_t)(b * HEAD_NUM + h) * NCHUNK + c;
    if (tid < D_K) {
        float r = 0.f;
        #pragma unroll
        for (int g = 0; g < 16; ++g) r += partial[g][tid];
        part_o[base * D_K + tid] = r;
    }
    if (tid == 0) {
        part_ml[base * 2 + 0] = m;
        part_ml[base * 2 + 1] = sum;
    }
}

// ---------------------------------------------------------------------------
// Kernel 3: combine chunk partials + new-token (s = start_pos) term.
// ---------------------------------------------------------------------------
__global__ __launch_bounds__(128) void combine_kernel(
    const float* __restrict__ qkv,
    const float* __restrict__ part_o,
    const float* __restrict__ part_ml,
    float* __restrict__ attn_out)
{
    const int h   = blockIdx.x;
    const int b   = blockIdx.y;
    const int tid = threadIdx.x;     // 0..127
    __shared__ float redS[2];

    const float* q    = qkv + b * HIDDEN + h * D_K;
    const float* knew = qkv + 1 * (MAX_BS * HIDDEN) + b * HIDDEN + h * D_K;
    const float* vnew = qkv + 2 * (MAX_BS * HIDDEN) + b * HIDDEN + h * D_K;

    float pp = q[tid] * knew[tid];
    #pragma unroll
    for (int off = 32; off; off >>= 1) pp += __shfl_xor(pp, off);
    if ((tid & 63) == 0) redS[tid >> 6] = pp;
    __syncthreads();
    const float score = (redS[0] + redS[1]) * 0.08838834764831845f;

    const size_t base = (size_t)(b * HEAD_NUM + h) * NCHUNK;
    float mv[NCHUNK];
    float M = score;
    #pragma unroll
    for (int c = 0; c < NCHUNK; ++c) {
        mv[c] = part_ml[(base + c) * 2];
        M = fmaxf(M, mv[c]);
    }
    float acc = 0.f, l = 0.f;
    #pragma unroll
    for (int c = 0; c < NCHUNK; ++c) {
        const float w = __expf(mv[c] - M);
        acc += w * part_o[(base + c) * D_K + tid];
        l   += w * part_ml[(base + c) * 2 + 1];
    }
    const float wn = __expf(score - M);
    acc += wn * vnew[tid];
    l   += wn;

    attn_out[b * HIDDEN + h * D_K + tid] = acc / l;
}

// ---------------------------------------------------------------------------
// Kernel 4: out = attn_out @ w_o. k-split x32 (512 blocks), atomics into
// memset-zeroed d_out. (R2-measured structure.)
// ---------------------------------------------------------------------------
__global__ __launch_bounds__(256) void oproj_kernel(
    const float* __restrict__ attn_out,
    const float* __restrict__ w_o,
    float* __restrict__ out)
{
    __shared__ float xs[MAX_BS][128];
    const int colTile = blockIdx.x;   // 0..15
    const int kChunk  = blockIdx.y;   // 0..31
    const int tid     = threadIdx.x;

    for (int idx = tid; idx < MAX_BS * 128 / 4; idx += 256) {
        int b = idx >> 5;
        int f = idx & 31;
        *reinterpret_cast<float4*>(&xs[b][f * 4]) =
            *reinterpret_cast<const float4*>(&attn_out[b * HIDDEN + kChunk * 128 + f * 4]);
    }
    __syncthreads();

    const int col = colTile * 256 + tid;
    float acc[MAX_BS];
    #pragma unroll
    for (int b = 0; b < MAX_BS; ++b) acc[b] = 0.f;

    const float* wcol = w_o + (size_t)(kChunk * 128) * HIDDEN + col;
    #pragma unroll 4
    for (int ii = 0; ii < 128; ++ii) {
        float w = wcol[(size_t)ii * HIDDEN];
        #pragma unroll
        for (int b = 0; b < MAX_BS; ++b)
            acc[b] = fmaf(xs[b][ii], w, acc[b]);
    }

    #pragma unroll
    for (int b = 0; b < MAX_BS; ++b)
        atomicAdd(&out[b * HIDDEN + col], acc[b]);
}

extern "C" void kernel_launch(void* const* d_in, const int* in_sizes, int n_in,
                              void* d_out, int out_size, void* d_ws, size_t ws_size,
                              hipStream_t stream) {
    const float* x       = (const float*)d_in[0];
    const float* cache_k = (const float*)d_in[1];
    const float* cache_v = (const float*)d_in[2];
    const float* w_q     = (const float*)d_in[3];
    const float* w_k     = (const float*)d_in[4];
    const float* w_v     = (const float*)d_in[5];
    const float* w_o     = (const float*)d_in[6];
    const int*   start_pos = (const int*)d_in[7];

    float* out      = (float*)d_out;
    float* qkv      = (float*)d_ws;                          // [3][16][4096]
    float* attn_out = qkv + 3 * MAX_BS * HIDDEN;             // [16][4096]
    float* part_o   = attn_out + MAX_BS * HIDDEN;            // [16][32][8][128]
    float* part_ml  = part_o + (size_t)MAX_BS * HEAD_NUM * NCHUNK * D_K; // [16][32][8][2]

    hipMemsetAsync(qkv, 0, (size_t)3 * MAX_BS * HIDDEN * sizeof(float), stream);
    hipMemsetAsync(d_out, 0, (size_t)out_size * sizeof(float), stream);

    qkv_kernel<<<dim3(16, 32, 3), 256, 0, stream>>>(x, w_q, w_k, w_v, qkv);
    attn_partial_kernel<<<dim3(HEAD_NUM, MAX_BS, NCHUNK), 256, 0, stream>>>(
        cache_k, cache_v, qkv, start_pos, part_o, part_ml);
    combine_kernel<<<dim3(HEAD_NUM, MAX_BS), 128, 0, stream>>>(
        qkv, part_o, part_ml, attn_out);
    oproj_kernel<<<dim3(16, 32), 256, 0, stream>>>(attn_out, w_o, out);
}